// Round 6
// baseline (1280.616 us; speedup 1.0000x reference)
//
#include <hip/hip_runtime.h>

#define N_NODES 50000
#define IN_DIM  3000
#define HID     512
#define LAT     30
#define N_EDGES 800000
#define M_PAD   50048   // 391*128
#define K1_PAD  3008    // 94*32
#define N4_PAD  3072    // 24*128

typedef __bf16 bf16;
typedef unsigned int uint;
typedef __attribute__((ext_vector_type(4))) float f32x4;
typedef __attribute__((ext_vector_type(8))) bf16 bf16x8;

__device__ __forceinline__ float bf2f(bf16 b){ return (float)b; }

__device__ __forceinline__ void gl16(const void* g, void* l){
  __builtin_amdgcn_global_load_lds(
      (const __attribute__((address_space(1))) void*)g,
      (__attribute__((address_space(3))) void*)l, 16, 0, 0);
}

// bijective XCD-aware swizzle (m204)
__device__ __forceinline__ int xcd_swz(int orig, int nwg){
  int q = nwg >> 3, r = nwg & 7;
  int xcd = orig & 7, lid = orig >> 3;
  return (xcd < r ? xcd*(q+1) : r*(q+1) + (xcd-r)*q) + lid;
}

__device__ __forceinline__ bf16x8 cvt8v(f32x4 a, f32x4 b){
  bf16x8 r;
  r[0]=(bf16)a[0]; r[1]=(bf16)a[1]; r[2]=(bf16)a[2]; r[3]=(bf16)a[3];
  r[4]=(bf16)b[0]; r[5]=(bf16)b[1]; r[6]=(bf16)b[2]; r[7]=(bf16)b[3];
  return r;
}

// ---------------- weight prep ----------------
__global__ void k_w1t(const float* __restrict__ W1, bf16* __restrict__ W1T){
  int k = blockIdx.x*256 + threadIdx.x;
  int n = blockIdx.y;
  if (k >= K1_PAD) return;
  float v = (k < IN_DIM) ? W1[(long)k*HID + n] : 0.f;
  W1T[(long)n*K1_PAD + k] = (bf16)v;
}
__global__ void k_w1p(const float* __restrict__ W1, bf16* __restrict__ W1P){
  int k = blockIdx.x*256 + threadIdx.x;
  int n = blockIdx.y;
  if (k >= HID) return;
  float v = (n < IN_DIM) ? W1[(long)n*HID + k] : 0.f;
  W1P[(long)n*HID + k] = (bf16)v;
}
__global__ void k_w2t(const float* __restrict__ W2, bf16* __restrict__ W2T){
  int k = blockIdx.x*256 + threadIdx.x;
  int n = blockIdx.y;
  if (k >= HID) return;
  float v = (n < LAT) ? W2[(long)k*LAT + n] : 0.f;
  W2T[(long)n*HID + k] = (bf16)v;
}
__global__ void k_w2p(const float* __restrict__ W2, bf16* __restrict__ W2P){
  int t = blockIdx.x*256 + threadIdx.x;
  if (t >= HID*32) return;
  int n = t >> 5, k = t & 31;
  W2P[t] = (bf16)((k < LAT) ? W2[(long)n*LAT + k] : 0.f);
}

// ---- gemm1: h1 = (fp32 x) @ W1T^T -- 2-phase double-buffered pipeline ----
// STAGE(next buf) issued BEFORE compute of current; ONE vmcnt(0)+barrier per
// K-step, placed AFTER the MFMA cluster (T3-minimum recipe).
__global__ __launch_bounds__(256) void gemm_xw1(
    const float* __restrict__ X, const bf16* __restrict__ Bw, bf16* __restrict__ C)
{
  __shared__ float Af[2][128*32];   // 2 x 16 KB
  __shared__ bf16  Bl[2][128*32];   // 2 x 8 KB
  const int NBX = HID/128;          // 4
  const int tid  = threadIdx.x;
  const int lane = tid & 63;
  const int w    = tid >> 6;
  const int wm   = (w >> 1) * 64, wn = (w & 1) * 64;
  const int wgid = xcd_swz(blockIdx.x, gridDim.x);
  const int col0 = (wgid % NBX) * 128, row0 = (wgid / NBX) * 128;

  f32x4 acc[4][4];
  #pragma unroll
  for (int mi=0;mi<4;mi++)
    #pragma unroll
    for (int ni=0;ni<4;ni++)
      acc[mi][ni] = (f32x4){0.f,0.f,0.f,0.f};

  // A staging: call i covers LDS rows i*32..i*32+31; thread -> (row, chunk)
  const int ar  = tid >> 3;               // row within call (0..31)
  const int apc = tid & 7;                // physical 16B chunk
  const int ac4 = (apc ^ (ar & 7)) * 4;   // logical element offset (swizzled)
  int aoff[4];
  #pragma unroll
  for (int i=0;i<4;i++)
    aoff[i] = min(row0 + i*32 + ar, N_NODES-1) * IN_DIM;

  // B staging (linear)
  const int sr = tid >> 2;
  const int sc = (tid & 3) * 16;
  const char* gB = (const char*)(Bw + (long)(col0 + sr) * K1_PAD) + sc;
  const long bstep = (long)64 * K1_PAD * 2;

#define STAGE1(buf, ks) do{                                             \
    int kcl_ = min((ks)*32 + ac4, IN_DIM-4);                            \
    char* lA_ = (char*)&Af[buf][0] + tid*16;                            \
    _Pragma("unroll")                                                   \
    for (int i_=0;i_<4;i_++)                                            \
      gl16(X + aoff[i_] + kcl_, lA_ + i_*4096);                         \
    char* lB_ = (char*)&Bl[buf][0] + sr*64 + sc;                        \
    gl16(gB + (long)(ks)*64,         lB_);                              \
    gl16(gB + (long)(ks)*64 + bstep, lB_ + 64*64);                      \
  }while(0)

  STAGE1(0, 0);
  asm volatile("s_waitcnt vmcnt(0)" ::: "memory");
  __builtin_amdgcn_s_barrier();

  for (int ks = 0; ks < 94; ks++){
    const int cur = ks & 1;
    if (ks + 1 < 94) STAGE1(cur^1, ks+1);

    const float* Ac = &Af[cur][0];
    const bf16*  Bc = &Bl[cur][0];
    const int g2 = (lane >> 4) * 2;
    bf16x8 af[4], bfr[4];
    #pragma unroll
    for (int mi=0;mi<4;mi++){
      int row = wm + mi*16 + (lane & 15);
      int rx  = row & 7;
      f32x4 f0 = *(const f32x4*)&Ac[row*32 + ((g2    ) ^ rx)*4];
      f32x4 f1 = *(const f32x4*)&Ac[row*32 + ((g2 + 1) ^ rx)*4];
      af[mi] = cvt8v(f0, f1);
    }
    #pragma unroll
    for (int ni=0;ni<4;ni++)
      bfr[ni] = *(const bf16x8*)&Bc[(wn + ni*16 + (lane & 15))*32 + (lane>>4)*8];
    #pragma unroll
    for (int mi=0;mi<4;mi++)
      #pragma unroll
      for (int ni=0;ni<4;ni++)
        acc[mi][ni] = __builtin_amdgcn_mfma_f32_16x16x32_bf16(af[mi], bfr[ni], acc[mi][ni], 0, 0, 0);

    asm volatile("s_waitcnt vmcnt(0)" ::: "memory");
    __builtin_amdgcn_s_barrier();
  }
#undef STAGE1

  const int crb  = (lane >> 4) * 4;
  const int ccol = lane & 15;
  #pragma unroll
  for (int mi=0;mi<4;mi++){
    #pragma unroll
    for (int v=0;v<4;v++){
      int r = row0 + wm + mi*16 + crb + v;
      if (r >= N_NODES) continue;
      #pragma unroll
      for (int ni=0;ni<4;ni++){
        int cc = col0 + wn + ni*16 + ccol;
        C[(long)r*HID + cc] = (bf16)acc[mi][ni][v];
      }
    }
  }
}

// ---------------- GEMM: C = A * B^T, 2-phase double-buffered ----------------
template<bool C_F32, bool ELU>
__global__ __launch_bounds__(256) void gemm_glds(
    const bf16* __restrict__ A, const bf16* __restrict__ B, void* __restrict__ Cp,
    int lda, int ldb, int Ksteps, int Mvalid, int Nvalid, int ldc, int NBX)
{
  __shared__ bf16 Alds[2][128*32];
  __shared__ bf16 Blds[2][128*32];
  const int tid  = threadIdx.x;
  const int lane = tid & 63;
  const int w    = tid >> 6;
  const int wm   = (w >> 1) * 64, wn = (w & 1) * 64;
  const int wgid = xcd_swz(blockIdx.x, gridDim.x);
  const int col0 = (wgid % NBX) * 128, row0 = (wgid / NBX) * 128;

  f32x4 acc[4][4];
  #pragma unroll
  for (int mi=0;mi<4;mi++)
    #pragma unroll
    for (int ni=0;ni<4;ni++)
      acc[mi][ni] = (f32x4){0.f,0.f,0.f,0.f};

  const int sr = tid >> 2;
  const int sc = (tid & 3) * 16;

  const char* ga = (const char*)(A + (long)(row0 + sr) * lda) + sc;
  const char* gb = (const char*)(B + (long)(col0 + sr) * ldb) + sc;
  const long astep = (long)64 * lda * 2;
  const long bstep = (long)64 * ldb * 2;

#define STAGE2(buf, ks) do{                                             \
    const long ko_ = (long)(ks) * 64;                                   \
    char* la_ = (char*)&Alds[buf][0] + sr*64 + sc;                      \
    char* lb_ = (char*)&Blds[buf][0] + sr*64 + sc;                      \
    gl16(ga + ko_,         la_);                                        \
    gl16(ga + ko_ + astep, la_ + 64*64);                                \
    gl16(gb + ko_,         lb_);                                        \
    gl16(gb + ko_ + bstep, lb_ + 64*64);                                \
  }while(0)

  STAGE2(0, 0);
  asm volatile("s_waitcnt vmcnt(0)" ::: "memory");
  __builtin_amdgcn_s_barrier();

  for (int ks = 0; ks < Ksteps; ks++){
    const int cur = ks & 1;
    if (ks + 1 < Ksteps) STAGE2(cur^1, ks+1);

    const bf16* Ac = &Alds[cur][0];
    const bf16* Bc = &Blds[cur][0];
    bf16x8 af[4], bfr[4];
    #pragma unroll
    for (int mi=0;mi<4;mi++)
      af[mi] = *(const bf16x8*)&Ac[(wm + mi*16 + (lane & 15))*32 + (lane>>4)*8];
    #pragma unroll
    for (int ni=0;ni<4;ni++)
      bfr[ni] = *(const bf16x8*)&Bc[(wn + ni*16 + (lane & 15))*32 + (lane>>4)*8];
    #pragma unroll
    for (int mi=0;mi<4;mi++)
      #pragma unroll
      for (int ni=0;ni<4;ni++)
        acc[mi][ni] = __builtin_amdgcn_mfma_f32_16x16x32_bf16(af[mi], bfr[ni], acc[mi][ni], 0, 0, 0);

    asm volatile("s_waitcnt vmcnt(0)" ::: "memory");
    __builtin_amdgcn_s_barrier();
  }
#undef STAGE2

  const int crb  = (lane >> 4) * 4;
  const int ccol = lane & 15;
  #pragma unroll
  for (int mi=0;mi<4;mi++){
    #pragma unroll
    for (int v=0;v<4;v++){
      int r = row0 + wm + mi*16 + crb + v;
      if (r >= Mvalid) continue;
      #pragma unroll
      for (int ni=0;ni<4;ni++){
        int c = col0 + wn + ni*16 + ccol;
        if (c >= Nvalid) continue;
        float val = acc[mi][ni][v];
        if (ELU) val = (val > 0.f) ? val : expm1f(val);
        if (C_F32) ((float*)Cp)[(long)r*ldc + c] = val;
        else       ((bf16*)Cp)[(long)r*ldc + c] = (bf16)val;
      }
    }
  }
}

// ---------------- attention dots ----------------
__global__ void k_attdots(const bf16* __restrict__ h1, const float* __restrict__ att_s,
                          const float* __restrict__ att_d, float* __restrict__ a_src,
                          float* __restrict__ a_dst){
  int gid = blockIdx.x * blockDim.x + threadIdx.x;
  int row = gid >> 6, lane = gid & 63;
  if (row >= N_NODES) return;
  bf16x8 hv = *(const bf16x8*)(h1 + (long)row*HID + lane*8);
  float s1 = 0.f, s2 = 0.f;
  #pragma unroll
  for (int j=0;j<8;j++){
    float h = bf2f(hv[j]);
    s1 = fmaf(h, att_s[lane*8+j], s1);
    s2 = fmaf(h, att_d[lane*8+j], s2);
  }
  #pragma unroll
  for (int o=32;o>0;o>>=1){ s1 += __shfl_down(s1,o); s2 += __shfl_down(s2,o); }
  if (lane == 0){ a_src[row] = s1; a_dst[row] = s2; }
}

// ---------------- CSR build ----------------
__global__ void k_deg(const int* __restrict__ ei, int* __restrict__ deg){
  int e = blockIdx.x*256 + threadIdx.x;
  if (e >= N_EDGES) return;
  atomicAdd(&deg[ei[N_EDGES + e]], 1);
}

__global__ void k_scan(const int* __restrict__ deg, int* __restrict__ off, int* __restrict__ cur){
  const int n = M_PAD, T = 1024;
  int t = threadIdx.x;
  const int per = (n + T - 1) / T;
  int s0 = t*per, s1 = min(n, s0+per);
  int sum = 0;
  for (int i=s0;i<s1;i++) sum += deg[i];
  __shared__ int sd[1024];
  sd[t] = sum; __syncthreads();
  for (int o=1;o<T;o<<=1){
    int x = (t>=o) ? sd[t-o] : 0;
    __syncthreads();
    sd[t] += x;
    __syncthreads();
  }
  int run = sd[t] - sum;
  for (int i=s0;i<s1;i++){
    off[i] = run; cur[i] = run;
    run += deg[i];
  }
  if (s0 < n && s1 == n) off[n] = run;
}

// fill CSR and compute unnormalized p = exp(leaky(a_src+a_dst)) per slot.
__global__ void k_fill(const int* __restrict__ ei, int* __restrict__ cur,
                       int* __restrict__ csr_src, const float* __restrict__ a_s,
                       const float* __restrict__ a_d, float* __restrict__ p_e){
  int e = blockIdx.x*256 + threadIdx.x;
  if (e >= N_EDGES) return;
  int s = ei[e];
  int d = ei[N_EDGES + e];
  int pos = atomicAdd(&cur[d], 1);
  csr_src[pos] = s;
  float v = a_s[s] + a_d[d];
  v = (v > 0.f) ? v : 0.2f*v;
  p_e[pos] = __expf(v);
}

// ---------------- conv1 aggregation (no reductions) ----------------
__global__ __launch_bounds__(512) void k_agg1(
    const int* __restrict__ off, const int* __restrict__ csr_src,
    const float* __restrict__ p_edge,
    const bf16* __restrict__ h1, bf16* __restrict__ x1,
    float* __restrict__ s_node)
{
  const int i = blockIdx.x;
  const int t = threadIdx.x;
  const int start = off[i];
  const int deg = off[i+1] - start;
  __shared__ float p_sh[512];
  __shared__ int   s_sh[512];

  float acc = 0.f, ssum = 0.f;
  for (int base=0; base<deg; base+=512){
    int cnt = min(512, deg-base);
    if (t < cnt){
      p_sh[t] = p_edge[start+base+t];
      s_sh[t] = csr_src[start+base+t];
    }
    __syncthreads();
    for (int k=0;k<cnt;k++){
      float pk = p_sh[k];
      ssum += pk;
      acc = fmaf(pk, bf2f(h1[(long)s_sh[k]*HID + t]), acc);
    }
    __syncthreads();
  }
  float val = acc / (ssum + 1e-16f);
  val = (val > 0.f) ? val : expm1f(val);
  x1[(long)i*HID + t] = (bf16)val;
  if (t == 0) s_node[i] = ssum;
}

// ---------------- conv3 aggregate ----------------
__global__ void k_agg3(const int* __restrict__ off, const int* __restrict__ csr_src,
                       const float* __restrict__ p_edge, const float* __restrict__ s_node,
                       const float* __restrict__ x2, bf16* __restrict__ aggb)
{
  int i = blockIdx.x*8 + (threadIdx.x >> 5);
  int lane = threadIdx.x & 31;
  if (i >= M_PAD) return;
  float acc = 0.f;
  if (i < N_NODES){
    int s0 = off[i], d = off[i+1] - s0;
    for (int k=0;k<d;k++){
      int s = csr_src[s0+k];
      float pk = p_edge[s0+k];
      if (lane < LAT) acc = fmaf(pk, x2[(long)s*LAT + lane], acc);
    }
    acc *= 1.f/(s_node[i] + 1e-16f);
  }
  aggb[(long)i*32 + lane] = (bf16)((lane < LAT) ? acc : 0.f);
}

// ---------------- launch ----------------
extern "C" void kernel_launch(void* const* d_in, const int* in_sizes, int n_in,
                              void* d_out, int out_size, void* d_ws, size_t ws_size,
                              hipStream_t stream)
{
  const float* x     = (const float*)d_in[0];
  const int*   ei    = (const int*)d_in[1];
  const float* W1    = (const float*)d_in[2];
  const float* W2    = (const float*)d_in[3];
  const float* att_s = (const float*)d_in[4];
  const float* att_d = (const float*)d_in[5];

  float* out_x2 = (float*)d_out;                        // [N,30]
  float* out_x4 = (float*)d_out + (long)N_NODES*LAT;    // [N,3000] region

  // transient scratch inside the (not-yet-written) x4 region of d_out
  bf16* h1 = (bf16*)out_x4;                             // [M_PAD][HID]
  bf16* x1 = h1 + (long)M_PAD*HID;

  char* w = (char*)d_ws;
  bf16* W1T = (bf16*)w;  w += (long)HID*K1_PAD*2;
  bf16* W1P = (bf16*)w;  w += (long)N4_PAD*HID*2;
  bf16* W2T = (bf16*)w;  w += (long)128*HID*2;
  bf16* W2P = (bf16*)w;  w += (long)HID*32*2;
  bf16* x3  = (bf16*)w;  w += (long)M_PAD*HID*2;
  bf16* aggb= (bf16*)w;  w += (long)M_PAD*32*2;
  int* deg  = (int*)w;   w += (long)M_PAD*4;
  int* offs = (int*)w;   w += (long)(M_PAD+64)*4;
  int* cur  = (int*)w;   w += (long)M_PAD*4;
  int* csr  = (int*)w;   w += (long)N_EDGES*4;
  float* p_e = (float*)w; w += (long)N_EDGES*4;
  float* s_n = (float*)w; w += (long)M_PAD*4;
  float* a_s = (float*)w; w += (long)M_PAD*4;
  float* a_d = (float*)w; w += (long)M_PAD*4;

  // weight prep
  k_w1t<<<dim3((K1_PAD+255)/256, HID), 256, 0, stream>>>(W1, W1T);
  k_w1p<<<dim3((HID+255)/256, N4_PAD), 256, 0, stream>>>(W1, W1P);
  k_w2t<<<dim3(2, 128), 256, 0, stream>>>(W2, W2T);
  k_w2p<<<(HID*32+255)/256, 256, 0, stream>>>(W2, W2P);

  // CSR degree + offsets (independent of gemm1)
  hipMemsetAsync(deg, 0, (size_t)M_PAD*4, stream);
  k_deg<<<(N_EDGES+255)/256, 256, 0, stream>>>(ei, deg);
  k_scan<<<1, 1024, 0, stream>>>(deg, offs, cur);

  // h1 = x @ W1  (fp32-A-in-LDS, 2-phase pipeline)
  gemm_xw1<<<(M_PAD/128)*(HID/128), 256, 0, stream>>>(x, W1T, h1);

  k_attdots<<<(N_NODES*64)/256, 256, 0, stream>>>(h1, att_s, att_d, a_s, a_d);

  // CSR fill + fused edge softmax numerator
  k_fill<<<(N_EDGES+255)/256, 256, 0, stream>>>(ei, cur, csr, a_s, a_d, p_e);

  k_agg1<<<N_NODES, 512, 0, stream>>>(offs, csr, p_e, h1, x1, s_n);

  // x2 = x1 @ W2 -> fp32 out
  gemm_glds<true,false><<<1*(M_PAD/128), 256, 0, stream>>>(
      x1, W2T, out_x2, HID, HID, HID/32, N_NODES, LAT, LAT, 1);

  // conv3: aggregate on 30-wide x2, then x3 = elu(aggb @ W2P^T)
  k_agg3<<<(M_PAD+7)/8, 256, 0, stream>>>(offs, csr, p_e, s_n, out_x2, aggb);
  gemm_glds<false,true><<<(HID/128)*(M_PAD/128), 256, 0, stream>>>(
      aggb, W2P, x3, 32, 32, 1, M_PAD, HID, HID, HID/128);

  // x4 = x3 @ W1^T -> fp32 out (overwrites h1/x1 scratch)
  gemm_glds<true,false><<<(N4_PAD/128)*(M_PAD/128), 256, 0, stream>>>(
      x3, W1P, out_x4, HID, HID, HID/32, N_NODES, IN_DIM, IN_DIM, N4_PAD/128);
}

// Round 7
// 1205.490 us; speedup vs baseline: 1.0623x; 1.0623x over previous
//
#include <hip/hip_runtime.h>

#define N_NODES 50000
#define IN_DIM  3000
#define HID     512
#define LAT     30
#define N_EDGES 800000
#define M_PAD   50048   // 391*128
#define K1_PAD  3008    // 47*64
#define N4_PAD  3072    // 24*128

typedef __bf16 bf16;
typedef unsigned int uint;
typedef __attribute__((ext_vector_type(4))) float f32x4;
typedef __attribute__((ext_vector_type(8))) bf16 bf16x8;

__device__ __forceinline__ float bf2f(bf16 b){ return (float)b; }

__device__ __forceinline__ void gl16(const void* g, void* l){
  __builtin_amdgcn_global_load_lds(
      (const __attribute__((address_space(1))) void*)g,
      (__attribute__((address_space(3))) void*)l, 16, 0, 0);
}

// bijective XCD-aware swizzle (m204)
__device__ __forceinline__ int xcd_swz(int orig, int nwg){
  int q = nwg >> 3, r = nwg & 7;
  int xcd = orig & 7, lid = orig >> 3;
  return (xcd < r ? xcd*(q+1) : r*(q+1) + (xcd-r)*q) + lid;
}

__device__ __forceinline__ bf16x8 cvt8v(f32x4 a, f32x4 b){
  bf16x8 r;
  r[0]=(bf16)a[0]; r[1]=(bf16)a[1]; r[2]=(bf16)a[2]; r[3]=(bf16)a[3];
  r[4]=(bf16)b[0]; r[5]=(bf16)b[1]; r[6]=(bf16)b[2]; r[7]=(bf16)b[3];
  return r;
}

// ---------------- weight prep ----------------
// W1T: [n][K1_PAD] bf16, zero-pad k>=IN_DIM, stored CHUNK-SWIZZLED within each
// 64-col tile: chunk c=(k%64)/8 stored at p = c ^ (n&7). Staging is linear;
// ds_read applies the same XOR -> conflict-free LDS reads.
__global__ void k_w1t(const float* __restrict__ W1, bf16* __restrict__ W1T){
  int k = blockIdx.x*256 + threadIdx.x;
  int n = blockIdx.y;
  if (k >= K1_PAD) return;
  float v = (k < IN_DIM) ? W1[(long)k*HID + n] : 0.f;
  int kt = k >> 6, c = (k >> 3) & 7, off = k & 7;
  int p = c ^ (n & 7);
  W1T[(long)n*K1_PAD + kt*64 + p*8 + off] = (bf16)v;
}
__global__ void k_w1p(const float* __restrict__ W1, bf16* __restrict__ W1P){
  int k = blockIdx.x*256 + threadIdx.x;
  int n = blockIdx.y;
  if (k >= HID) return;
  float v = (n < IN_DIM) ? W1[(long)n*HID + k] : 0.f;
  W1P[(long)n*HID + k] = (bf16)v;
}
__global__ void k_w2t(const float* __restrict__ W2, bf16* __restrict__ W2T){
  int k = blockIdx.x*256 + threadIdx.x;
  int n = blockIdx.y;
  if (k >= HID) return;
  float v = (n < LAT) ? W2[(long)k*LAT + n] : 0.f;
  W2T[(long)n*HID + k] = (bf16)v;
}
__global__ void k_w2p(const float* __restrict__ W2, bf16* __restrict__ W2P){
  int t = blockIdx.x*256 + threadIdx.x;
  if (t >= HID*32) return;
  int n = t >> 5, k = t & 31;
  W2P[t] = (bf16)((k < LAT) ? W2[(long)n*LAT + k] : 0.f);
}

// ---- gemm1: h1 = (fp32 x) @ W1T^T ----
// BK=64 single-buffered m97 structure (47 K-steps, 32 MFMA per barrier pair).
// A fp32 [128][64] LDS, XOR-chunk-swizzled via inverse-swizzled global src;
// B bf16 [128][64] LDS, swizzle pre-baked in W1T layout (linear staging).
__global__ __launch_bounds__(256) void gemm_xw1(
    const float* __restrict__ X, const bf16* __restrict__ Bw, bf16* __restrict__ C)
{
  __shared__ float Af[128*64];   // 32 KB
  __shared__ bf16  Bl[128*64];   // 16 KB
  const int NBX = HID/128;       // 4
  const int tid  = threadIdx.x;
  const int lane = tid & 63;
  const int w    = tid >> 6;
  const int wm   = (w >> 1) * 64, wn = (w & 1) * 64;
  const int wgid = xcd_swz(blockIdx.x, gridDim.x);
  const int col0 = (wgid % NBX) * 128, row0 = (wgid / NBX) * 128;

  f32x4 acc[4][4];
  #pragma unroll
  for (int mi=0;mi<4;mi++)
    #pragma unroll
    for (int ni=0;ni<4;ni++)
      acc[mi][ni] = (f32x4){0.f,0.f,0.f,0.f};

  // A staging: call i covers LDS slot i*256+tid -> row = i*16 + (tid>>4),
  // physical chunk ap = tid&15 (constant). Inverse swizzle: logical chunk
  // al = (ap&8) | ((ap&7) ^ (row&7)); row&7 = (tid>>4)&7 (i*16 = 0 mod 8).
  const int ap = tid & 15;
  const int al = (ap & 8) | ((ap & 7) ^ ((tid >> 4) & 7));
  int arb[8];
  #pragma unroll
  for (int i=0;i<8;i++)
    arb[i] = min(row0 + i*16 + (tid >> 4), N_NODES-1) * IN_DIM;

  // B staging: call i covers slot i*256+tid -> row = i*32 + (tid>>3),
  // chunk p = tid&7; W1T is pre-swizzled so staging is linear.
  int brb[4];
  #pragma unroll
  for (int i=0;i<4;i++)
    brb[i] = (col0 + i*32 + (tid >> 3)) * K1_PAD + (tid & 7)*8;

  char* lA = (char*)Af + tid*16;
  char* lB = (char*)Bl + tid*16;
  const int g  = lane >> 4;
  const int rl = lane & 15;

  for (int ks = 0; ks < 47; ks++){
    const int kb = ks * 64;
    const int ka = min(kb + al*4, IN_DIM-4);   // clamp: junk cols meet B=0
    #pragma unroll
    for (int i=0;i<8;i++) gl16(X + arb[i] + ka, lA + i*4096);
    #pragma unroll
    for (int i=0;i<4;i++) gl16(Bw + brb[i] + kb, lB + i*4096);
    __syncthreads();   // drains vmcnt -> tile ready

    #pragma unroll
    for (int ksub=0; ksub<2; ksub++){
      bf16x8 af[4], bfr[4];
      #pragma unroll
      for (int mi=0;mi<4;mi++){
        int r  = wm + mi*16 + rl;
        int rx = r & 7;
        int l0 = ksub*8 + g*2;
        int p0 = (l0 & 8)     | ((l0 & 7) ^ rx);
        int p1 = ((l0+1) & 8) | (((l0+1) & 7) ^ rx);
        f32x4 f0 = *(const f32x4*)((const char*)Af + r*256 + p0*16);
        f32x4 f1 = *(const f32x4*)((const char*)Af + r*256 + p1*16);
        af[mi] = cvt8v(f0, f1);
      }
      #pragma unroll
      for (int ni=0;ni<4;ni++){
        int r = wn + ni*16 + rl;
        int p = (ksub*4 + g) ^ (r & 7);
        bfr[ni] = *(const bf16x8*)((const char*)Bl + r*128 + p*16);
      }
      #pragma unroll
      for (int mi=0;mi<4;mi++)
        #pragma unroll
        for (int ni=0;ni<4;ni++)
          acc[mi][ni] = __builtin_amdgcn_mfma_f32_16x16x32_bf16(af[mi], bfr[ni], acc[mi][ni], 0, 0, 0);
    }
    __syncthreads();   // protect LDS before next stage
  }

  const int crb  = (lane >> 4) * 4;
  const int ccol = lane & 15;
  #pragma unroll
  for (int mi=0;mi<4;mi++){
    #pragma unroll
    for (int v=0;v<4;v++){
      int r = row0 + wm + mi*16 + crb + v;
      if (r >= N_NODES) continue;
      #pragma unroll
      for (int ni=0;ni<4;ni++){
        int cc = col0 + wn + ni*16 + ccol;
        C[(long)r*HID + cc] = (bf16)acc[mi][ni][v];
      }
    }
  }
}

// ---------------- GEMM (m97 structure): C = A * B^T, flat grid + swizzle ----
template<bool C_F32, bool ELU>
__global__ __launch_bounds__(256) void gemm_glds(
    const bf16* __restrict__ A, const bf16* __restrict__ B, void* __restrict__ Cp,
    int lda, int ldb, int Ksteps, int Mvalid, int Nvalid, int ldc, int NBX)
{
  __shared__ bf16 Alds[128*32];
  __shared__ bf16 Blds[128*32];
  const int tid  = threadIdx.x;
  const int lane = tid & 63;
  const int w    = tid >> 6;
  const int wm   = (w >> 1) * 64, wn = (w & 1) * 64;
  const int wgid = xcd_swz(blockIdx.x, gridDim.x);
  const int col0 = (wgid % NBX) * 128, row0 = (wgid / NBX) * 128;

  f32x4 acc[4][4];
  #pragma unroll
  for (int mi=0;mi<4;mi++)
    #pragma unroll
    for (int ni=0;ni<4;ni++)
      acc[mi][ni] = (f32x4){0.f,0.f,0.f,0.f};

  const int sr = tid >> 2;
  const int sc = (tid & 3) * 16;

  const char* ga = (const char*)(A + (long)(row0 + sr) * lda) + sc;
  const char* gb = (const char*)(B + (long)(col0 + sr) * ldb) + sc;
  char* la = (char*)Alds + sr*64 + sc;
  char* lb = (char*)Blds + sr*64 + sc;
  const long astep = (long)64 * lda * 2;
  const long bstep = (long)64 * ldb * 2;

  for (int ks = 0; ks < Ksteps; ks++){
    const long ko = (long)ks * 64;
    gl16(ga + ko,         la);
    gl16(ga + ko + astep, la + 64*64);
    gl16(gb + ko,         lb);
    gl16(gb + ko + bstep, lb + 64*64);
    __syncthreads();

    bf16x8 af[4], bfr[4];
    #pragma unroll
    for (int mi=0;mi<4;mi++)
      af[mi] = *(const bf16x8*)&Alds[(wm + mi*16 + (lane & 15))*32 + (lane>>4)*8];
    #pragma unroll
    for (int ni=0;ni<4;ni++)
      bfr[ni] = *(const bf16x8*)&Blds[(wn + ni*16 + (lane & 15))*32 + (lane>>4)*8];
    #pragma unroll
    for (int mi=0;mi<4;mi++)
      #pragma unroll
      for (int ni=0;ni<4;ni++)
        acc[mi][ni] = __builtin_amdgcn_mfma_f32_16x16x32_bf16(af[mi], bfr[ni], acc[mi][ni], 0, 0, 0);
    __syncthreads();
  }

  const int crb  = (lane >> 4) * 4;
  const int ccol = lane & 15;
  #pragma unroll
  for (int mi=0;mi<4;mi++){
    #pragma unroll
    for (int v=0;v<4;v++){
      int r = row0 + wm + mi*16 + crb + v;
      if (r >= Mvalid) continue;
      #pragma unroll
      for (int ni=0;ni<4;ni++){
        int c = col0 + wn + ni*16 + ccol;
        if (c >= Nvalid) continue;
        float val = acc[mi][ni][v];
        if (ELU) val = (val > 0.f) ? val : expm1f(val);
        if (C_F32) ((float*)Cp)[(long)r*ldc + c] = val;
        else       ((bf16*)Cp)[(long)r*ldc + c] = (bf16)val;
      }
    }
  }
}

// ---------------- attention dots ----------------
__global__ void k_attdots(const bf16* __restrict__ h1, const float* __restrict__ att_s,
                          const float* __restrict__ att_d, float* __restrict__ a_src,
                          float* __restrict__ a_dst){
  int gid = blockIdx.x * blockDim.x + threadIdx.x;
  int row = gid >> 6, lane = gid & 63;
  if (row >= N_NODES) return;
  bf16x8 hv = *(const bf16x8*)(h1 + (long)row*HID + lane*8);
  float s1 = 0.f, s2 = 0.f;
  #pragma unroll
  for (int j=0;j<8;j++){
    float h = bf2f(hv[j]);
    s1 = fmaf(h, att_s[lane*8+j], s1);
    s2 = fmaf(h, att_d[lane*8+j], s2);
  }
  #pragma unroll
  for (int o=32;o>0;o>>=1){ s1 += __shfl_down(s1,o); s2 += __shfl_down(s2,o); }
  if (lane == 0){ a_src[row] = s1; a_dst[row] = s2; }
}

// ---------------- CSR build ----------------
__global__ void k_deg(const int* __restrict__ ei, int* __restrict__ deg){
  int e = blockIdx.x*256 + threadIdx.x;
  if (e >= N_EDGES) return;
  atomicAdd(&deg[ei[N_EDGES + e]], 1);
}

__global__ void k_scan(const int* __restrict__ deg, int* __restrict__ off, int* __restrict__ cur){
  const int n = M_PAD, T = 1024;
  int t = threadIdx.x;
  const int per = (n + T - 1) / T;
  int s0 = t*per, s1 = min(n, s0+per);
  int sum = 0;
  for (int i=s0;i<s1;i++) sum += deg[i];
  __shared__ int sd[1024];
  sd[t] = sum; __syncthreads();
  for (int o=1;o<T;o<<=1){
    int x = (t>=o) ? sd[t-o] : 0;
    __syncthreads();
    sd[t] += x;
    __syncthreads();
  }
  int run = sd[t] - sum;
  for (int i=s0;i<s1;i++){
    off[i] = run; cur[i] = run;
    run += deg[i];
  }
  if (s0 < n && s1 == n) off[n] = run;
}

// fill CSR and compute unnormalized p = exp(leaky(a_src+a_dst)) per slot.
__global__ void k_fill(const int* __restrict__ ei, int* __restrict__ cur,
                       int* __restrict__ csr_src, const float* __restrict__ a_s,
                       const float* __restrict__ a_d, float* __restrict__ p_e){
  int e = blockIdx.x*256 + threadIdx.x;
  if (e >= N_EDGES) return;
  int s = ei[e];
  int d = ei[N_EDGES + e];
  int pos = atomicAdd(&cur[d], 1);
  csr_src[pos] = s;
  float v = a_s[s] + a_d[d];
  v = (v > 0.f) ? v : 0.2f*v;
  p_e[pos] = __expf(v);
}

// ---------------- conv1 aggregation (no reductions) ----------------
__global__ __launch_bounds__(512) void k_agg1(
    const int* __restrict__ off, const int* __restrict__ csr_src,
    const float* __restrict__ p_edge,
    const bf16* __restrict__ h1, bf16* __restrict__ x1,
    float* __restrict__ s_node)
{
  const int i = blockIdx.x;
  const int t = threadIdx.x;
  const int start = off[i];
  const int deg = off[i+1] - start;
  __shared__ float p_sh[512];
  __shared__ int   s_sh[512];

  float acc = 0.f, ssum = 0.f;
  for (int base=0; base<deg; base+=512){
    int cnt = min(512, deg-base);
    if (t < cnt){
      p_sh[t] = p_edge[start+base+t];
      s_sh[t] = csr_src[start+base+t];
    }
    __syncthreads();
    for (int k=0;k<cnt;k++){
      float pk = p_sh[k];
      ssum += pk;
      acc = fmaf(pk, bf2f(h1[(long)s_sh[k]*HID + t]), acc);
    }
    __syncthreads();
  }
  float val = acc / (ssum + 1e-16f);
  val = (val > 0.f) ? val : expm1f(val);
  x1[(long)i*HID + t] = (bf16)val;
  if (t == 0) s_node[i] = ssum;
}

// ---------------- conv3 aggregate ----------------
__global__ void k_agg3(const int* __restrict__ off, const int* __restrict__ csr_src,
                       const float* __restrict__ p_edge, const float* __restrict__ s_node,
                       const float* __restrict__ x2, bf16* __restrict__ aggb)
{
  int i = blockIdx.x*8 + (threadIdx.x >> 5);
  int lane = threadIdx.x & 31;
  if (i >= M_PAD) return;
  float acc = 0.f;
  if (i < N_NODES){
    int s0 = off[i], d = off[i+1] - s0;
    for (int k=0;k<d;k++){
      int s = csr_src[s0+k];
      float pk = p_edge[s0+k];
      if (lane < LAT) acc = fmaf(pk, x2[(long)s*LAT + lane], acc);
    }
    acc *= 1.f/(s_node[i] + 1e-16f);
  }
  aggb[(long)i*32 + lane] = (bf16)((lane < LAT) ? acc : 0.f);
}

// ---------------- launch ----------------
extern "C" void kernel_launch(void* const* d_in, const int* in_sizes, int n_in,
                              void* d_out, int out_size, void* d_ws, size_t ws_size,
                              hipStream_t stream)
{
  const float* x     = (const float*)d_in[0];
  const int*   ei    = (const int*)d_in[1];
  const float* W1    = (const float*)d_in[2];
  const float* W2    = (const float*)d_in[3];
  const float* att_s = (const float*)d_in[4];
  const float* att_d = (const float*)d_in[5];

  float* out_x2 = (float*)d_out;                        // [N,30]
  float* out_x4 = (float*)d_out + (long)N_NODES*LAT;    // [N,3000] region

  // transient scratch inside the (not-yet-written) x4 region of d_out
  bf16* h1 = (bf16*)out_x4;                             // [M_PAD][HID]
  bf16* x1 = h1 + (long)M_PAD*HID;

  char* w = (char*)d_ws;
  bf16* W1T = (bf16*)w;  w += (long)HID*K1_PAD*2;
  bf16* W1P = (bf16*)w;  w += (long)N4_PAD*HID*2;
  bf16* W2T = (bf16*)w;  w += (long)128*HID*2;
  bf16* W2P = (bf16*)w;  w += (long)HID*32*2;
  bf16* x3  = (bf16*)w;  w += (long)M_PAD*HID*2;
  bf16* aggb= (bf16*)w;  w += (long)M_PAD*32*2;
  int* deg  = (int*)w;   w += (long)M_PAD*4;
  int* offs = (int*)w;   w += (long)(M_PAD+64)*4;
  int* cur  = (int*)w;   w += (long)M_PAD*4;
  int* csr  = (int*)w;   w += (long)N_EDGES*4;
  float* p_e = (float*)w; w += (long)N_EDGES*4;
  float* s_n = (float*)w; w += (long)M_PAD*4;
  float* a_s = (float*)w; w += (long)M_PAD*4;
  float* a_d = (float*)w; w += (long)M_PAD*4;

  // weight prep
  k_w1t<<<dim3((K1_PAD+255)/256, HID), 256, 0, stream>>>(W1, W1T);
  k_w1p<<<dim3((HID+255)/256, N4_PAD), 256, 0, stream>>>(W1, W1P);
  k_w2t<<<dim3(2, 128), 256, 0, stream>>>(W2, W2T);
  k_w2p<<<(HID*32+255)/256, 256, 0, stream>>>(W2, W2P);

  // CSR degree + offsets (independent of gemm1)
  hipMemsetAsync(deg, 0, (size_t)M_PAD*4, stream);
  k_deg<<<(N_EDGES+255)/256, 256, 0, stream>>>(ei, deg);
  k_scan<<<1, 1024, 0, stream>>>(deg, offs, cur);

  // h1 = x @ W1  (BK=64, conflict-free swizzled LDS)
  gemm_xw1<<<(M_PAD/128)*(HID/128), 256, 0, stream>>>(x, W1T, h1);

  k_attdots<<<(N_NODES*64)/256, 256, 0, stream>>>(h1, att_s, att_d, a_s, a_d);

  // CSR fill + fused edge softmax numerator
  k_fill<<<(N_EDGES+255)/256, 256, 0, stream>>>(ei, cur, csr, a_s, a_d, p_e);

  k_agg1<<<N_NODES, 512, 0, stream>>>(offs, csr, p_e, h1, x1, s_n);

  // x2 = x1 @ W2 -> fp32 out
  gemm_glds<true,false><<<1*(M_PAD/128), 256, 0, stream>>>(
      x1, W2T, out_x2, HID, HID, HID/32, N_NODES, LAT, LAT, 1);

  // conv3: aggregate on 30-wide x2, then x3 = elu(aggb @ W2P^T)
  k_agg3<<<(M_PAD+7)/8, 256, 0, stream>>>(offs, csr, p_e, s_n, out_x2, aggb);
  gemm_glds<false,true><<<(HID/128)*(M_PAD/128), 256, 0, stream>>>(
      aggb, W2P, x3, 32, 32, 1, M_PAD, HID, HID, HID/128);

  // x4 = x3 @ W1^T -> fp32 out (overwrites h1/x1 scratch)
  gemm_glds<true,false><<<(N4_PAD/128)*(M_PAD/128), 256, 0, stream>>>(
      x3, W1P, out_x4, HID, HID, HID/32, N_NODES, IN_DIM, IN_DIM, N4_PAD/128);
}